// Round 12
// baseline (102.530 us; speedup 1.0000x reference)
//
#include <hip/hip_runtime.h>
#include <math.h>

#define F_    16
#define NV_   4096
#define NT_   512
#define M_    4096
#define PPF_  (NV_ + NT_)        // 4608 points per frame
#define NPTS_ (F_ * PPF_)        // 73728 total points
#define SCALE_INV 10.0f          // 1 / 0.1

#define TPB   256
#define PTSB  72                 // 64 blocks/frame (no straddle); 1024 blocks = 4/CU EXACT (no tail)
#define NBLK  (NPTS_ / PTSB)     // 1024
#define NG    64                 // model groups (g = t>>2, 4 lanes each) -> 64 ds_read events/wave (halved vs R10)
#define MPG   (M_ / NG)          // 64 models per group
#define CHM   16                 // models per group per chunk
#define NCH   (MPG / CHM)        // 4 chunks
#define FS    17                 // v4f stride/group: quad(g,m) = (g*17+m)&7 = (g+m)&7; 16 groups/wave -> 8 quads x2 = free
#define PPL   18                 // points per lane (4 point-lanes x 18 = 72)
#define NPR   9                  // f32 pairs per lane (even split, no pk waste)

typedef float v2f __attribute__((ext_vector_type(2)));
typedef float v4f __attribute__((ext_vector_type(4)));

// ---------------------------------------------------------------- pose math
__device__ inline void rot_from_omega(float ox, float oy, float oz, float dt,
                                      float* R) {
    // R = I + sin(theta*dt)*S + (1-cos(theta*dt))*S^2,  S = skew(omega/max(theta,1e-8))
    float theta = sqrtf(ox * ox + oy * oy + oz * oz);
    float inv = 1.0f / fmaxf(theta, 1e-8f);
    float ax = ox * inv, ay = oy * inv, az = oz * inv;
    float s = sinf(theta * dt);
    float c = 1.0f - cosf(theta * dt);
    R[0] = 1.0f - c * (ay * ay + az * az);
    R[1] = -s * az + c * ax * ay;
    R[2] =  s * ay + c * ax * az;
    R[3] =  s * az + c * ax * ay;
    R[4] = 1.0f - c * (ax * ax + az * az);
    R[5] = -s * ax + c * ay * az;
    R[6] = -s * ay + c * ax * az;
    R[7] =  s * ax + c * ay * az;
    R[8] = 1.0f - c * (ax * ax + ay * ay);
}

// ---------------------------------------------------------------- packed distance core (r7/r10-proven, absmax 0)
// 2 models (A,B) x 3 point-pairs: 18 v_pk_fma_f32 + 6 v_min3.
// z-stage acc = fma(-2gz, z, w); y-stage += -2gy*y; x-stage += -2gx*x.
__device__ __forceinline__ void dist6(v2f qa01, v2f qa23, v2f qb01, v2f qb23,
                                      v2f c0a, v2f c0b, v2f c0c,
                                      v2f c1a, v2f c1b, v2f c1c,
                                      v2f c2a, v2f c2b, v2f c2c, float* dmp) {
    v2f A0, A1, A2, B0, B1, B2;
    asm("v_pk_fma_f32 %0, %7, %16, %7 op_sel:[0,0,1] op_sel_hi:[0,1,1]\n\t"
        "v_pk_fma_f32 %1, %7, %17, %7 op_sel:[0,0,1] op_sel_hi:[0,1,1]\n\t"
        "v_pk_fma_f32 %2, %7, %18, %7 op_sel:[0,0,1] op_sel_hi:[0,1,1]\n\t"
        "v_pk_fma_f32 %3, %9, %16, %9 op_sel:[0,0,1] op_sel_hi:[0,1,1]\n\t"
        "v_pk_fma_f32 %4, %9, %17, %9 op_sel:[0,0,1] op_sel_hi:[0,1,1]\n\t"
        "v_pk_fma_f32 %5, %9, %18, %9 op_sel:[0,0,1] op_sel_hi:[0,1,1]\n\t"
        "v_pk_fma_f32 %0, %6, %13, %0 op_sel:[1,0,0] op_sel_hi:[1,1,1]\n\t"
        "v_pk_fma_f32 %1, %6, %14, %1 op_sel:[1,0,0] op_sel_hi:[1,1,1]\n\t"
        "v_pk_fma_f32 %2, %6, %15, %2 op_sel:[1,0,0] op_sel_hi:[1,1,1]\n\t"
        "v_pk_fma_f32 %3, %8, %13, %3 op_sel:[1,0,0] op_sel_hi:[1,1,1]\n\t"
        "v_pk_fma_f32 %4, %8, %14, %4 op_sel:[1,0,0] op_sel_hi:[1,1,1]\n\t"
        "v_pk_fma_f32 %5, %8, %15, %5 op_sel:[1,0,0] op_sel_hi:[1,1,1]\n\t"
        "v_pk_fma_f32 %0, %6, %10, %0 op_sel:[0,0,0] op_sel_hi:[0,1,1]\n\t"
        "v_pk_fma_f32 %1, %6, %11, %1 op_sel:[0,0,0] op_sel_hi:[0,1,1]\n\t"
        "v_pk_fma_f32 %2, %6, %12, %2 op_sel:[0,0,0] op_sel_hi:[0,1,1]\n\t"
        "v_pk_fma_f32 %3, %8, %10, %3 op_sel:[0,0,0] op_sel_hi:[0,1,1]\n\t"
        "v_pk_fma_f32 %4, %8, %11, %4 op_sel:[0,0,0] op_sel_hi:[0,1,1]\n\t"
        "v_pk_fma_f32 %5, %8, %12, %5 op_sel:[0,0,0] op_sel_hi:[0,1,1]"
        : "=&v"(A0), "=&v"(A1), "=&v"(A2), "=&v"(B0), "=&v"(B1), "=&v"(B2)
        : "v"(qa01), "v"(qa23), "v"(qb01), "v"(qb23),
          "v"(c0a), "v"(c0b), "v"(c0c),
          "v"(c1a), "v"(c1b), "v"(c1c),
          "v"(c2a), "v"(c2b), "v"(c2c));
    dmp[0] = fminf(fminf(A0.x, B0.x), dmp[0]);
    dmp[1] = fminf(fminf(A0.y, B0.y), dmp[1]);
    dmp[2] = fminf(fminf(A1.x, B1.x), dmp[2]);
    dmp[3] = fminf(fminf(A1.y, B1.y), dmp[3]);
    dmp[4] = fminf(fminf(A2.x, B2.x), dmp[4]);
    dmp[5] = fminf(fminf(A2.y, B2.y), dmp[5]);
}

// ---------------------------------------------------------------- fused kernel
// R12 combines the two levers the dataset isolated: pk core (busy 36.5->23.7us,
// R10) x 4 blocks/CU (stall 17.6->11.5us, R5) x halved ds_read events (NG=64).
// Structure otherwise identical to R10 (chunked LDS staging, reg-prefetch,
// per-thread pose, proven epilogue).
__global__ __launch_bounds__(TPB, 4) void chamfer_one(
    const float* __restrict__ state, const float* __restrict__ model,
    const float* __restrict__ vis, const float* __restrict__ tac,
    const float* __restrict__ phys, const float* __restrict__ dts,
    float* __restrict__ out) {
    __shared__ v4f   feat[NG * FS];         // 17.4 KB model features {-2g, |g|^2}
    __shared__ float sdm[PTSB][NG + 1];     // 18.7 KB per-point per-group mins (+1 pad)
    __shared__ float sw[2];

    const int t  = threadIdx.x;
    const int g  = t >> 2;                  // model group 0..63 (4 lanes each)
    const int pl = t & 3;                   // point-lane 0..3 (18 points each)
    const int f  = blockIdx.x >> 6;         // 64 blocks/frame
    const int lbase = (blockIdx.x & 63) * PTSB;

    // ---- stage chunk 0 early (hide under pose math); 4 entries per thread ----
#pragma unroll
    for (int j = 0; j < 4; ++j) {
        int e  = t + 256 * j;               // 0..1023: ge = e>>4, me = e&15
        int ge = e >> 4, me = e & 15;
        int id = ge * MPG + me;             // chunk 0
        float gx = model[id * 3 + 0], gy = model[id * 3 + 1], gz = model[id * 3 + 2];
        feat[ge * FS + me] =
            (v4f){-2.0f * gx, -2.0f * gy, -2.0f * gz, gx * gx + gy * gy + gz * gz};
    }

    // ---- pose for frame f, per-thread (uniform f -> no divergence; identical
    // op order to the reference scan) ----
    float R[9], tr[3];
    {
        tr[0] = state[0]; tr[1] = state[1]; tr[2] = state[2];
        rot_from_omega(state[3], state[4], state[5], 1.0f, R);
        for (int i = 1; i <= f; ++i) {
            float dt = dts[i];
            tr[0] += phys[i * 12 + 6] * dt;
            tr[1] += phys[i * 12 + 7] * dt;
            tr[2] += phys[i * 12 + 8] * dt;
            float Rs[9];
            rot_from_omega(phys[i * 12 + 9], phys[i * 12 + 10], phys[i * 12 + 11], dt, Rs);
            float Rn[9];
            for (int r = 0; r < 3; ++r)
                for (int c2 = 0; c2 < 3; ++c2)
                    Rn[r * 3 + c2] = Rs[r * 3 + 0] * R[0 + c2] +
                                     Rs[r * 3 + 1] * R[3 + c2] +
                                     Rs[r * 3 + 2] * R[6 + c2];
            for (int j = 0; j < 9; ++j) R[j] = Rn[j];
        }
        for (int j = 0; j < 9; ++j) R[j] *= SCALE_INV;  // fold 1/SCALE
    }

    // ---- transform my 18 points into 9 packed pairs ----
    v2f c0p[NPR], c1p[NPR], c2p[NPR];
    float cn[PPL], dm[PPL];
#pragma unroll
    for (int k = 0; k < PPL; ++k) {
        int loc = lbase + pl * PPL + k;
        const float* p = (loc < NV_) ? (vis + ((size_t)f * NV_ + loc) * 3)
                                     : (tac + ((size_t)f * NT_ + (loc - NV_)) * 3);
        float d0 = p[0] - tr[0], d1 = p[1] - tr[1], d2 = p[2] - tr[2];
        float x = d0 * R[0] + d1 * R[3] + d2 * R[6];
        float y = d0 * R[1] + d1 * R[4] + d2 * R[7];
        float z = d0 * R[2] + d1 * R[5] + d2 * R[8];
        cn[k] = x * x + y * y + z * z;
        dm[k] = 3.4e38f;
        if (k & 1) { c0p[k >> 1].y = x; c1p[k >> 1].y = y; c2p[k >> 1].y = z; }
        else       { c0p[k >> 1].x = x; c1p[k >> 1].x = y; c2p[k >> 1].x = z; }
    }
    __syncthreads();

    // ---- main loop: 4 chunks x 16 models/group; reg-prefetch next chunk ----
    for (int c = 0; c < NCH; ++c) {
        float mx[4], my[4], mz[4];
        if (c + 1 < NCH) {                  // issue next chunk's loads first
#pragma unroll
            for (int j = 0; j < 4; ++j) {
                int e  = t + 256 * j;
                int id = (e >> 4) * MPG + (c + 1) * CHM + (e & 15);
                mx[j] = model[id * 3 + 0];
                my[j] = model[id * 3 + 1];
                mz[j] = model[id * 3 + 2];
            }
        }
        const v4f* fb = &feat[g * FS];
#pragma unroll 4
        for (int m = 0; m < CHM; m += 2) {
            v4f ga = fb[m];                 // 16 addrs/wave, 2 per bank-quad = free
            v4f gb = fb[m + 1];
            v2f qa01 = (v2f){ga.x, ga.y}, qa23 = (v2f){ga.z, ga.w};
            v2f qb01 = (v2f){gb.x, gb.y}, qb23 = (v2f){gb.z, gb.w};
            dist6(qa01, qa23, qb01, qb23, c0p[0], c0p[1], c0p[2],
                  c1p[0], c1p[1], c1p[2], c2p[0], c2p[1], c2p[2], dm);
            dist6(qa01, qa23, qb01, qb23, c0p[3], c0p[4], c0p[5],
                  c1p[3], c1p[4], c1p[5], c2p[3], c2p[4], c2p[5], dm + 6);
            dist6(qa01, qa23, qb01, qb23, c0p[6], c0p[7], c0p[8],
                  c1p[6], c1p[7], c1p[8], c2p[6], c2p[7], c2p[8], dm + 12);
        }
        __syncthreads();                    // all reads of chunk c done
        if (c + 1 < NCH) {
#pragma unroll
            for (int j = 0; j < 4; ++j) {
                int e = t + 256 * j;
                feat[(e >> 4) * FS + (e & 15)] =
                    (v4f){-2.0f * mx[j], -2.0f * my[j], -2.0f * mz[j],
                          mx[j] * mx[j] + my[j] * my[j] + mz[j] * mz[j]};
            }
            __syncthreads();                // chunk c+1 staged
        }
    }

    // ---- combine 64 group-partials per point, weight, block-sum, one atomic ----
#pragma unroll
    for (int k = 0; k < PPL; ++k) sdm[pl * PPL + k][g] = dm[k] + cn[k];
    __syncthreads();

    float v = 0.0f;
    if (t < PTSB) {
        const float* row = sdm[t];
        float mn = row[0];
#pragma unroll 8
        for (int i = 1; i < NG; ++i) mn = fminf(mn, row[i]);
        const int loc = lbase + t;
        const float w = (loc < NV_) ? (1.0f / NV_) : (0.1f / NT_);
        v = mn * w;
    }
    if (t < 128) {
#pragma unroll
        for (int off = 32; off > 0; off >>= 1) v += __shfl_down(v, off);
        if ((t & 63) == 0) sw[t >> 6] = v;
    }
    __syncthreads();
    if (t == 0) atomicAdd(out, sw[0] + sw[1]);
}

// ---------------------------------------------------------------- launch
// d_ws unused: single fused kernel (multi-kernel structures lost to launch
// overhead, r8/r9); the 256MB ws poison fill runs unconditionally regardless.
extern "C" void kernel_launch(void* const* d_in, const int* in_sizes, int n_in,
                              void* d_out, int out_size, void* d_ws, size_t ws_size,
                              hipStream_t stream) {
    const float* state = (const float*)d_in[0];   // (6,)
    const float* model = (const float*)d_in[1];   // (M,3)
    const float* vis   = (const float*)d_in[2];   // (F,NV,3)
    const float* tac   = (const float*)d_in[3];   // (F,NT,3)
    const float* phys  = (const float*)d_in[4];   // (F,12)
    const float* dts   = (const float*)d_in[5];   // (F,)
    float* out = (float*)d_out;
    (void)d_ws; (void)ws_size;

    hipMemsetAsync(out, 0, sizeof(float), stream);
    chamfer_one<<<NBLK, TPB, 0, stream>>>(state, model, vis, tac, phys, dts, out);
}